// Round 2
// baseline (1783.088 us; speedup 1.0000x reference)
//
#include <hip/hip_runtime.h>
#include <hip/hip_bf16.h>
#include <stdint.h>

#define NB 512
#define NW 40
#define NE 512
#define NH 512
#define NV 12000
#define G4 2048

typedef unsigned short u16;
typedef __attribute__((ext_vector_type(8))) short short8;
typedef __attribute__((ext_vector_type(4))) float f32x4;

__device__ __forceinline__ unsigned short f2bf(float f) {
  unsigned int u = __float_as_uint(f);
  u += 0x7FFF + ((u >> 16) & 1);
  return (unsigned short)(u >> 16);
}
__device__ __forceinline__ float bf2f(unsigned short b) {
  return __uint_as_float(((unsigned int)b) << 16);
}
// flag==1: float inputs are actually bf16 on device; flag==0: fp32
__device__ __forceinline__ float loadIn(const void* p, long i, int bf) {
  return bf ? bf2f(((const u16*)p)[i]) : ((const float*)p)[i];
}

// ---------------- dtype detector ----------------
__global__ void detect_kernel(const u16* p, int* flag) {
  __shared__ int cnt;
  int i = threadIdx.x;
  if (i == 0) cnt = 0;
  __syncthreads();
  unsigned short u = p[2 * (i * 1001)];
  int e = (u >> 7) & 0xFF;
  if (e >= 100 && e <= 126) atomicAdd(&cnt, 1);
  __syncthreads();
  if (i == 0) *flag = (cnt >= 32) ? 1 : 0;
}

// ---------------- tableT = bf16(tanh(lookup_W^T)), (V, E) ----------------
__global__ void table_kernel(const void* lookup, const int* flag, u16* tableT) {
  __shared__ float tile[64][65];
  int bf = *flag;
  int v0 = blockIdx.x * 64, e0 = blockIdx.y * 64;
  int tx = threadIdx.x, ty = threadIdx.y;  // (64,4)
#pragma unroll
  for (int r = 0; r < 16; ++r) {
    int e = r * 4 + ty, v = tx;
    if (v0 + v < NV)
      tile[e][v] = tanhf(loadIn(lookup, (long)(e0 + e) * NV + v0 + v, bf));
  }
  __syncthreads();
#pragma unroll
  for (int r = 0; r < 16; ++r) {
    int v = r * 4 + ty, e = tx;
    if (v0 + v < NV)
      tableT[(long)(v0 + v) * NE + e0 + e] = f2bf(tile[e][v]);
  }
}

// ---------------- emb (W, B, E) bf16 ----------------
__global__ void embed_kernel(const int* __restrict__ qv,
                             const u16* __restrict__ tableT,
                             u16* __restrict__ emb) {
  int tid = blockIdx.x * 256 + threadIdx.x;
  int token = tid >> 6;
  int chunk = tid & 63;
  int tt = token / NB, b = token % NB;
  int q = qv[b * NW + tt];
  uint4 val = make_uint4(0u, 0u, 0u, 0u);
  if (q > 0) val = *(const uint4*)(tableT + (long)(q - 1) * NE + chunk * 8);
  *(uint4*)(emb + (long)token * NE + chunk * 8) = val;
}

// ---------------- pack weights: Wc[d] rows = [wih | whh], bf16 ------------
__global__ void pack_kernel(const void* wih0, const void* whh0, const void* b0,
                            const void* wih1, const void* whh1, const void* b1,
                            const int* flag, u16* Wc0, u16* Wc1, float* bsum) {
  const long N0 = 2L * G4 * 1024, N1 = 2L * G4 * 1536;
  long idx = (long)blockIdx.x * 256 + threadIdx.x;
  int bf = *flag;
  if (idx < N0) {
    int d = (int)(idx / (G4 * 1024));
    int rem = (int)(idx % (long)(G4 * 1024));
    int g = rem / 1024, k = rem % 1024;
    float v = (k < 512) ? loadIn(wih0, ((long)d * G4 + g) * 512 + k, bf)
                        : loadIn(whh0, ((long)d * G4 + g) * 512 + (k - 512), bf);
    Wc0[idx] = f2bf(v);
  } else if (idx < N0 + N1) {
    long i2 = idx - N0;
    int d = (int)(i2 / (G4 * 1536));
    int rem = (int)(i2 % (long)(G4 * 1536));
    int g = rem / 1536, k = rem % 1536;
    float v = (k < 1024) ? loadIn(wih1, ((long)d * G4 + g) * 1024 + k, bf)
                         : loadIn(whh1, ((long)d * G4 + g) * 512 + (k - 1024), bf);
    Wc1[i2] = f2bf(v);
  } else if (idx < N0 + N1 + 2L * 2 * G4) {
    long i3 = idx - N0 - N1;  // [layer][d][g]
    int layer = (int)(i3 / (2 * G4));
    int d = (int)((i3 / G4) & 1);
    int g = (int)(i3 % G4);
    const void* bb = layer ? b1 : b0;
    float v = loadIn(bb, (long)d * 2 * G4 + g, bf) +
              loadIn(bb, (long)d * 2 * G4 + G4 + g, bf);
    bsum[i3] = v;
  }
}

// ---------------- zero h (ping 0, both dirs) and c ----------------
__global__ void init_kernel(u16* h0, float* c) {
  int i = blockIdx.x * 256 + threadIdx.x;  // 2*512*512
  h0[i] = 0;
  c[i] = 0.f;
}

// ---------------- fused LSTM step ----------------
// Block tile: BM=64 batch x BN=128 rows (4 gates x 32 j), one dir.
// 4 waves in 2x2 grid, wave tile 32m x 64n, MFMA 16x16x32 bf16.
// Grid: 256 blocks, XCD-swizzled so 8 m-blocks of one weight column share
// an XCD (weights served from that XCD's L2 after first fetch).
__global__ __launch_bounds__(256, 2) void lstm_step(
    const u16* __restrict__ xf, const u16* __restrict__ xb, int Kx,
    const u16* __restrict__ hprev, u16* __restrict__ hnext,
    const u16* __restrict__ Wc, const float* __restrict__ bsumL,
    float* __restrict__ cst, u16* __restrict__ h0cat, void* __restrict__ outp,
    const int* __restrict__ qlen, const int* __restrict__ flag, int t,
    int layer) {
  __shared__ __align__(16) char lds[49152];  // 2 x (A 8KB + B 16KB); epi 32KB
  const int tid = threadIdx.x;
  const int lane = tid & 63, wv = tid >> 6;
  const int wm = wv & 1, wn = wv >> 1;  // wave grid 2(m) x 2(n)
  const int col = lane & 15, quad = lane >> 4;

  // XCD-aware decode: linear id l -> xcd = l%8 (round-robin heuristic).
  const int l = blockIdx.x;                 // [0,256)
  const int xcd = l & 7, slot = l >> 3;     // slot [0,32)
  const int mi = slot & 7;                  // m-block [0,8)
  const int colid = xcd + 8 * (slot >> 3);  // weight column [0,32)
  const int j0 = (colid & 15) * 32;
  const int d = colid >> 4;

  const int m0 = mi * 64;
  const int K = Kx + 512;
  const u16* xd = d ? xb : xf;
  const u16* hp = hprev + d * (NB * NH);
  const u16* Wd = Wc + (long)d * G4 * K;

  f32x4 zero = {0.f, 0.f, 0.f, 0.f};
  f32x4 acc[2][4];
#pragma unroll
  for (int i = 0; i < 2; ++i)
#pragma unroll
    for (int j = 0; j < 4; ++j) acc[i][j] = zero;

  const int iters = K >> 6;

  // ---- staging: A 64x64 + B 128x64 bf16 = 24KB, 6 passes x 256 lanes ----
  auto stage = [&](int it, int pb) {
    int k0 = it << 6;
    char* dst = lds + pb * 24576;
#pragma unroll
    for (int p = 0; p < 6; ++p) {
      int c = p * 256 + tid;  // [0,1536)
      const u16* gsrc;
      if (c < 512) {  // A tile rows 0..63
        int r = c >> 3, seg = (c & 7) << 3;
        int kk = k0 + (seg ^ ((r & 7) << 3));  // XOR swizzle (bank fix)
        gsrc = (kk < Kx) ? xd + (long)(m0 + r) * Kx + kk
                         : hp + (long)(m0 + r) * NH + (kk - Kx);
      } else {  // B rows 0..127 = gate*32 + jj
        int cb = c - 512;
        int br = cb >> 3, seg = (cb & 7) << 3;
        int kk = k0 + (seg ^ ((br & 7) << 3));
        gsrc = Wd + (long)((br >> 5) * 512 + j0 + (br & 31)) * K + kk;
      }
      __builtin_amdgcn_global_load_lds(
          (const __attribute__((address_space(1))) void*)(const void*)gsrc,
          (__attribute__((address_space(3))) void*)(dst + p * 4096 + wv * 1024),
          16, 0, 0);
    }
  };

  int pb = 0;
  stage(0, 0);
  __syncthreads();
  for (int it = 0; it < iters; ++it) {
    if (it + 1 < iters) stage(it + 1, pb ^ 1);  // overlap with compute
    const u16* As = (const u16*)(lds + pb * 24576);
    const u16* Bs = As + 4096;  // +8KB
#pragma unroll
    for (int ks = 0; ks < 2; ++ks) {
      short8 afr[2], bfr[4];
#pragma unroll
      for (int mf = 0; mf < 2; ++mf) {
        int rm = wm * 32 + mf * 16 + col;
        int sl = (ks * 32 + quad * 8) ^ ((rm & 7) << 3);
        afr[mf] = *(const short8*)(As + rm * 64 + sl);
      }
#pragma unroll
      for (int nf = 0; nf < 4; ++nf) {
        int br = wn * 64 + nf * 16 + col;
        int sl = (ks * 32 + quad * 8) ^ ((br & 7) << 3);
        bfr[nf] = *(const short8*)(Bs + br * 64 + sl);
      }
#pragma unroll
      for (int mf = 0; mf < 2; ++mf)
#pragma unroll
        for (int nf = 0; nf < 4; ++nf)
          acc[mf][nf] = __builtin_amdgcn_mfma_f32_16x16x32_bf16(
              afr[mf], bfr[nf], acc[mf][nf], 0, 0, 0);
    }
    __syncthreads();  // drains next-buf loads too
    pb ^= 1;
  }

  // ---- gates -> LDS fp32 [gate][64 m][32 n] = 32 KB ----
  float* L = (float*)lds;
  float bias[4];
#pragma unroll
  for (int nf = 0; nf < 4; ++nf) {
    int nn = wn * 64 + nf * 16 + col;
    bias[nf] = bsumL[d * G4 + (nn >> 5) * 512 + j0 + (nn & 31)];
  }
#pragma unroll
  for (int mf = 0; mf < 2; ++mf)
#pragma unroll
    for (int nf = 0; nf < 4; ++nf) {
      int nn = wn * 64 + nf * 16 + col;
      int gt = nn >> 5, jn = nn & 31;
#pragma unroll
      for (int r = 0; r < 4; ++r) {
        int m = wm * 32 + mf * 16 + quad * 4 + r;
        L[(gt * 64 + m) * 32 + jn] = acc[mf][nf][r] + bias[nf];
      }
    }
  __syncthreads();

  int isbf = *flag;
#pragma unroll
  for (int p = 0; p < 8; ++p) {
    int e = p * 256 + tid;  // 64*32 cells
    int m = e >> 5, n = e & 31;
    float gi = L[(0 * 64 + m) * 32 + n];
    float gf = L[(1 * 64 + m) * 32 + n];
    float gg = L[(2 * 64 + m) * 32 + n];
    float go = L[(3 * 64 + m) * 32 + n];
    int bg = m0 + m, jg = j0 + n;
    float* cp = cst + ((long)d * NB + bg) * NH + jg;
    float cold = *cp;
    float si = 1.f / (1.f + __expf(-gi));
    float sf = 1.f / (1.f + __expf(-gf));
    float so = 1.f / (1.f + __expf(-go));
    float cn = sf * cold + si * tanhf(gg);
    float h = so * tanhf(cn);
    *cp = cn;
    hnext[((long)d * NB + bg) * NH + jg] = f2bf(h);
    int tt = d ? (NW - 1 - t) : t;
    if (layer == 0) {
      h0cat[((long)tt * NB + bg) * (2 * NH) + d * NH + jg] = f2bf(h);
    } else {
      if (qlen[bg] - 1 == tt) {
        long oi = (long)bg * (2 * NH) + d * NH + jg;
        if (isbf)
          ((u16*)outp)[oi] = f2bf(h);
        else
          ((float*)outp)[oi] = h;
      }
    }
  }
}

extern "C" void kernel_launch(void* const* d_in, const int* in_sizes, int n_in,
                              void* d_out, int out_size, void* d_ws,
                              size_t ws_size, hipStream_t stream) {
  const int* qv = (const int*)d_in[0];
  const int* ql = (const int*)d_in[1];
  const void* lookup = d_in[2];
  const void* wih0 = d_in[3];
  const void* whh0 = d_in[4];
  const void* b0 = d_in[5];
  const void* wih1 = d_in[6];
  const void* whh1 = d_in[7];
  const void* b1 = d_in[8];

  char* ws = (char*)d_ws;
  size_t off = 0;
  int* flag = (int*)ws;
  off += 256;
  u16* tableT = (u16*)(ws + off); off += (size_t)NV * NE * 2;
  u16* emb = (u16*)(ws + off);    off += (size_t)NW * NB * NE * 2;
  u16* h0cat = (u16*)(ws + off);  off += (size_t)NW * NB * 2 * NH * 2;
  u16* Wc0 = (u16*)(ws + off);    off += 2L * G4 * 1024 * 2;
  u16* Wc1 = (u16*)(ws + off);    off += 2L * G4 * 1536 * 2;
  float* bsum = (float*)(ws + off); off += 2L * 2 * G4 * 4;
  u16* hbuf = (u16*)(ws + off);   off += 2L * 2 * NB * NH * 2;
  float* cbuf = (float*)(ws + off); off += 2L * NB * NH * 4;

  detect_kernel<<<1, 64, 0, stream>>>((const u16*)lookup, flag);
  table_kernel<<<dim3(188, 8), dim3(64, 4), 0, stream>>>(lookup, flag, tableT);
  {
    long total = 2L * G4 * 1024 + 2L * G4 * 1536 + 2L * 2 * G4;
    int blocks = (int)((total + 255) / 256);
    pack_kernel<<<blocks, 256, 0, stream>>>(wih0, whh0, b0, wih1, whh1, b1,
                                            flag, Wc0, Wc1, bsum);
  }
  embed_kernel<<<NW * NB / 4, 256, 0, stream>>>(qv, tableT, emb);

  const size_t HB = (size_t)2 * NB * NH;

  // layer 0
  init_kernel<<<2048, 256, 0, stream>>>(hbuf, cbuf);
  for (int t = 0; t < NW; ++t) {
    const u16* hpp = hbuf + (size_t)(t & 1) * HB;
    u16* hnn = hbuf + (size_t)((t + 1) & 1) * HB;
    lstm_step<<<256, 256, 0, stream>>>(
        emb + (size_t)t * NB * NE, emb + (size_t)(NW - 1 - t) * NB * NE, NE,
        hpp, hnn, Wc0, bsum, cbuf, h0cat, d_out, ql, flag, t, 0);
  }
  // layer 1
  init_kernel<<<2048, 256, 0, stream>>>(hbuf, cbuf);
  for (int t = 0; t < NW; ++t) {
    const u16* hpp = hbuf + (size_t)(t & 1) * HB;
    u16* hnn = hbuf + (size_t)((t + 1) & 1) * HB;
    lstm_step<<<256, 256, 0, stream>>>(
        h0cat + (size_t)t * NB * 2 * NH,
        h0cat + (size_t)(NW - 1 - t) * NB * 2 * NH, 2 * NH,
        hpp, hnn, Wc1, bsum + 2 * G4, cbuf, h0cat, d_out, ql, flag, t, 1);
  }
}